// Round 1
// baseline (320.854 us; speedup 1.0000x reference)
//
#include <hip/hip_runtime.h>
#include <math.h>

// Problem constants
#define IMG 28
#define NPP 169            // 13*13 patches per image
#define M_TOTAL (1024*NPP) // 173056 patches
#define FEAT 1521          // 169*9

// One wave (64 lanes) simulates one patch's 512-amplitude state vector.
// Basis index d = lane*8 + r  (d in [0,512)).
// Reference bit convention: bit of wire w is bit (8-w) of d.
//   wires 0..5 -> lane bits 5..0 (shfl_xor masks 32,16,8,4,2,1)
//   wires 6..8 -> register bits 2,1,0 (r xor 4,2,1)
__global__ __launch_bounds__(256) void quanv_kernel(const float* __restrict__ x,
                                                    const float* __restrict__ qp,
                                                    float* __restrict__ feats) {
    const int wave = (blockIdx.x * blockDim.x + threadIdx.x) >> 6;
    const int lane = threadIdx.x & 63;
    if (wave >= M_TOTAL) return;
    const int img = wave / NPP;
    const int rem = wave - img * NPP;
    const int pr  = rem / 13;
    const int pc  = rem - pr * 13;
    const float* base = x + img * (IMG*IMG) + (pr * 2) * IMG + pc * 2;

    // --- data-encoding angles: 3x3 patch, wire w = a*3 + c ---
    float cw[9], sw[9];
    #pragma unroll
    for (int a = 0; a < 3; ++a)
        #pragma unroll
        for (int c = 0; c < 3; ++c) {
            float h = 0.5f * base[a * IMG + c];
            cw[a*3+c] = __cosf(h);
            sw[a*3+c] = __sinf(h);
        }

    // --- parameterized rotation half-angle cos/sin (wave-uniform) ---
    float qc[11], qs[11];
    #pragma unroll
    for (int p = 0; p < 11; ++p) {
        float h = 0.5f * qp[p];
        qc[p] = __cosf(h);
        qs[p] = __sinf(h);
    }

    // --- initial product state: amp[d] = prod_w (bit_w(d) ? sin : cos) ---
    float L = 1.0f;
    #pragma unroll
    for (int w = 0; w < 6; ++w)
        L *= ((lane >> (5 - w)) & 1) ? sw[w] : cw[w];
    float re[8], im[8];
    #pragma unroll
    for (int r = 0; r < 8; ++r) {
        float f = L;
        f *= ((r >> 2) & 1) ? sw[6] : cw[6];
        f *= ((r >> 1) & 1) ? sw[7] : cw[7];
        f *= ( r       & 1) ? sw[8] : cw[8];
        re[r] = f;
        im[r] = 0.0f;
    }

    // --- gate helpers ---
    auto ry_lane = [&](int m, float c, float s) {
        float sg = (lane & m) ? s : -s;
        #pragma unroll
        for (int r = 0; r < 8; ++r) {
            float pre = __shfl_xor(re[r], m);
            float pim = __shfl_xor(im[r], m);
            re[r] = c * re[r] + sg * pre;
            im[r] = c * im[r] + sg * pim;
        }
    };
    auto rx_lane = [&](int m, float c, float s) {
        #pragma unroll
        for (int r = 0; r < 8; ++r) {
            float pre = __shfl_xor(re[r], m);
            float pim = __shfl_xor(im[r], m);
            re[r] = c * re[r] + s * pim;
            im[r] = c * im[r] - s * pre;
        }
    };
    auto rz_lane = [&](int m, float c, float s) {
        float sg = (lane & m) ? s : -s;   // bit0: *(c - i s); bit1: *(c + i s)
        #pragma unroll
        for (int r = 0; r < 8; ++r) {
            float nr = c * re[r] - sg * im[r];
            im[r]    = c * im[r] + sg * re[r];
            re[r]    = nr;
        }
    };
    auto cnot_ll = [&](int cm, int tm) {  // ctrl lane-bit cm, tgt lane-mask tm
        #pragma unroll
        for (int r = 0; r < 8; ++r) {
            float pre = __shfl_xor(re[r], tm);
            float pim = __shfl_xor(im[r], tm);
            re[r] = (lane & cm) ? pre : re[r];
            im[r] = (lane & cm) ? pim : im[r];
        }
    };
    auto ry_reg = [&](int rm, float c, float s) {
        float nre[8], nim[8];
        #pragma unroll
        for (int r = 0; r < 8; ++r) {
            float sg = (r & rm) ? s : -s;
            nre[r] = c * re[r] + sg * re[r ^ rm];
            nim[r] = c * im[r] + sg * im[r ^ rm];
        }
        #pragma unroll
        for (int r = 0; r < 8; ++r) { re[r] = nre[r]; im[r] = nim[r]; }
    };
    auto rx_reg = [&](int rm, float c, float s) {
        float nre[8], nim[8];
        #pragma unroll
        for (int r = 0; r < 8; ++r) {
            nre[r] = c * re[r] + s * im[r ^ rm];
            nim[r] = c * im[r] - s * re[r ^ rm];
        }
        #pragma unroll
        for (int r = 0; r < 8; ++r) { re[r] = nre[r]; im[r] = nim[r]; }
    };
    auto rz_reg = [&](int rm, float c, float s) {
        #pragma unroll
        for (int r = 0; r < 8; ++r) {
            float sg = (r & rm) ? s : -s;
            float nr = c * re[r] - sg * im[r];
            im[r]    = c * im[r] + sg * re[r];
            re[r]    = nr;
        }
    };

    // --- circuit: OPS with q_params in order ---
    ry_lane(32, qc[0],  qs[0]);   // ry w0
    rx_lane(4,  qc[1],  qs[1]);   // rx w3
    cnot_ll(32, 16);              // cnot 0,1
    rz_lane(1,  qc[2],  qs[2]);   // rz w5
    ry_reg(2,   qc[3],  qs[3]);   // ry w7
    cnot_ll(8,  4);               // cnot 2,3
    rx_lane(16, qc[4],  qs[4]);   // rx w1
    rz_reg(1,   qc[5],  qs[5]);   // rz w8
    cnot_ll(2,  1);               // cnot 4,5
    ry_lane(8,  qc[6],  qs[6]);   // ry w2
    rx_reg(4,   qc[7],  qs[7]);   // rx w6
    {                              // cnot 6,7: ctrl r&4, tgt r^2 -> swap (4,6),(5,7)
        float t;
        t = re[4]; re[4] = re[6]; re[6] = t;
        t = im[4]; im[4] = im[6]; im[6] = t;
        t = re[5]; re[5] = re[7]; re[7] = t;
        t = im[5]; im[5] = im[7]; im[7] = t;
    }
    rz_lane(2,  qc[8],  qs[8]);   // rz w4
    ry_reg(1,   qc[9],  qs[9]);   // ry w8
    {                              // cnot 8,0: ctrl r&1, tgt lane^32
        #pragma unroll
        for (int r = 1; r < 8; r += 2) {
            re[r] = __shfl_xor(re[r], 32);
            im[r] = __shfl_xor(im[r], 32);
        }
    }
    rx_lane(1,  qc[10], qs[10]);  // rx w5

    // --- expectations <Z_w> = sum_d (1-2*bit_w(d)) |amp[d]|^2 ---
    float prob[8];
    float ptot = 0.0f;
    #pragma unroll
    for (int r = 0; r < 8; ++r) {
        prob[r] = re[r] * re[r] + im[r] * im[r];
        ptot += prob[r];
    }
    float acc[9];
    #pragma unroll
    for (int w = 0; w < 6; ++w)
        acc[w] = (lane & (32 >> w)) ? -ptot : ptot;
    acc[6] = 0.0f; acc[7] = 0.0f; acc[8] = 0.0f;
    #pragma unroll
    for (int r = 0; r < 8; ++r) {
        acc[6] += (r & 4) ? -prob[r] : prob[r];
        acc[7] += (r & 2) ? -prob[r] : prob[r];
        acc[8] += (r & 1) ? -prob[r] : prob[r];
    }
    #pragma unroll
    for (int m = 1; m < 64; m <<= 1) {
        #pragma unroll
        for (int w = 0; w < 9; ++w)
            acc[w] += __shfl_xor(acc[w], m);
    }
    if (lane == 0) {
        #pragma unroll
        for (int w = 0; w < 9; ++w)
            feats[wave * 9 + w] = acc[w];
    }
}

// One wave per image: 2 dot products of length 1521 + bias + log_softmax.
__global__ __launch_bounds__(256) void head_kernel(const float* __restrict__ feats,
                                                   const float* __restrict__ W,
                                                   const float* __restrict__ bias,
                                                   float* __restrict__ out) {
    const int wave = (blockIdx.x * blockDim.x + threadIdx.x) >> 6;
    const int lane = threadIdx.x & 63;
    if (wave >= 1024) return;
    const float* f = feats + wave * FEAT;
    float s0 = 0.0f, s1 = 0.0f;
    for (int j = lane; j < FEAT; j += 64) {
        float v = f[j];
        s0 += v * W[j];
        s1 += v * W[FEAT + j];
    }
    #pragma unroll
    for (int m = 1; m < 64; m <<= 1) {
        s0 += __shfl_xor(s0, m);
        s1 += __shfl_xor(s1, m);
    }
    if (lane == 0) {
        float l0 = s0 + bias[0];
        float l1 = s1 + bias[1];
        float mx  = fmaxf(l0, l1);
        float lse = mx + logf(expf(l0 - mx) + expf(l1 - mx));
        out[wave * 2 + 0] = l0 - lse;
        out[wave * 2 + 1] = l1 - lse;
    }
}

extern "C" void kernel_launch(void* const* d_in, const int* in_sizes, int n_in,
                              void* d_out, int out_size, void* d_ws, size_t ws_size,
                              hipStream_t stream) {
    const float* x  = (const float*)d_in[0];   // (1024,1,28,28)
    const float* qp = (const float*)d_in[1];   // (11,)
    const float* W  = (const float*)d_in[2];   // (2,1521)
    const float* b  = (const float*)d_in[3];   // (2,)
    float* out   = (float*)d_out;              // (1024,2) f32
    float* feats = (float*)d_ws;               // 1024*1521 f32 = 6.23 MB

    quanv_kernel<<<M_TOTAL / 4, 256, 0, stream>>>(x, qp, feats);
    head_kernel<<<1024 / 4, 256, 0, stream>>>(feats, W, b, out);
}

// Round 2
// 192.690 us; speedup vs baseline: 1.6651x; 1.6651x over previous
//
#include <hip/hip_runtime.h>
#include <math.h>

// Problem constants
#define IMG 28
#define NPP 169            // 13*13 patches per image
#define M_TOTAL (1024*NPP) // 173056 patches
#define FEAT 1521          // 169*9

__device__ __forceinline__ float rfl(float v) {
    return __int_as_float(__builtin_amdgcn_readfirstlane(__float_as_int(v)));
}

// 4 patches per wave; 16 lanes per patch; 32 complex amplitudes per lane.
// Basis index d = (lane&15)*32 + r, r in [0,32). Wire w <-> bit (8-w) of d:
//   w0..w3 -> lane bits 3..0 (shfl_xor masks 8,4,2,1 — stay within 16-group)
//   w4..w8 -> register bits 4..0 (rm = 16,8,4,2,1)
__global__ __launch_bounds__(256) void quanv_kernel(const float* __restrict__ x,
                                                    const float* __restrict__ qp,
                                                    float* __restrict__ feats) {
    const int wid  = (blockIdx.x * blockDim.x + threadIdx.x) >> 6;
    const int lane = threadIdx.x & 63;
    const int sub  = lane >> 4;     // patch-in-wave
    const int l4   = lane & 15;     // lane-in-patch
    const int patch = wid * 4 + sub;
    const int img = patch / NPP;
    const int rem = patch - img * NPP;
    const int pr  = rem / 13;
    const int pc  = rem - pr * 13;
    const float* base = x + img * (IMG*IMG) + (pr * 2) * IMG + pc * 2;

    // --- per-patch data-encoding trig (wire w = a*3 + c) ---
    float cw[9], sw[9];
    #pragma unroll
    for (int a = 0; a < 3; ++a)
        #pragma unroll
        for (int c = 0; c < 3; ++c) {
            float h = 0.5f * base[a * IMG + c];
            cw[a*3+c] = __cosf(h);
            sw[a*3+c] = __sinf(h);
        }

    // --- parameter trig, wave-uniform -> SGPRs ---
    float qc[11], qs[11];
    #pragma unroll
    for (int p = 0; p < 11; ++p) {
        float h = 0.5f * qp[p];
        qc[p] = rfl(__cosf(h));
        qs[p] = rfl(__sinf(h));
    }

    // --- initial product state ---
    float L = 1.0f;
    L *= (l4 & 8) ? sw[0] : cw[0];
    L *= (l4 & 4) ? sw[1] : cw[1];
    L *= (l4 & 2) ? sw[2] : cw[2];
    L *= (l4 & 1) ? sw[3] : cw[3];
    float Lf[4];
    Lf[0] = L * (cw[4]*cw[5]); Lf[1] = L * (cw[4]*sw[5]);
    Lf[2] = L * (sw[4]*cw[5]); Lf[3] = L * (sw[4]*sw[5]);
    float f678[8];
    #pragma unroll
    for (int i = 0; i < 8; ++i)
        f678[i] = ((i&4)?sw[6]:cw[6]) * ((i&2)?sw[7]:cw[7]) * ((i&1)?sw[8]:cw[8]);
    float re[32], im[32];
    #pragma unroll
    for (int r = 0; r < 32; ++r) {
        re[r] = Lf[r >> 3] * f678[r & 7];
        im[r] = 0.0f;
    }

    // --- gate helpers (same math as verified round-1 kernel) ---
    auto ry_lane = [&](int m, float c, float s) {
        float sg = (l4 & m) ? s : -s;
        #pragma unroll
        for (int r = 0; r < 32; ++r) {
            float pre = __shfl_xor(re[r], m);
            float pim = __shfl_xor(im[r], m);
            re[r] = c * re[r] + sg * pre;
            im[r] = c * im[r] + sg * pim;
        }
    };
    auto rx_lane = [&](int m, float c, float s) {
        #pragma unroll
        for (int r = 0; r < 32; ++r) {
            float pre = __shfl_xor(re[r], m);
            float pim = __shfl_xor(im[r], m);
            re[r] = c * re[r] + s * pim;
            im[r] = c * im[r] - s * pre;
        }
    };
    auto cnot_ll = [&](int cm, int tm) {
        const bool ctrl = (l4 & cm) != 0;
        #pragma unroll
        for (int r = 0; r < 32; ++r) {
            float pre = __shfl_xor(re[r], tm);
            float pim = __shfl_xor(im[r], tm);
            re[r] = ctrl ? pre : re[r];
            im[r] = ctrl ? pim : im[r];
        }
    };
    auto ry_reg = [&](int rm, float c, float s) {
        #pragma unroll
        for (int r = 0; r < 32; ++r) {
            if (!(r & rm)) {
                int q = r | rm;
                float a0 = re[r], a1 = re[q], b0 = im[r], b1 = im[q];
                re[r] = c * a0 - s * a1;  re[q] = s * a0 + c * a1;
                im[r] = c * b0 - s * b1;  im[q] = s * b0 + c * b1;
            }
        }
    };
    auto rx_reg = [&](int rm, float c, float s) {
        #pragma unroll
        for (int r = 0; r < 32; ++r) {
            if (!(r & rm)) {
                int q = r | rm;
                float a0 = re[r], a1 = re[q], b0 = im[r], b1 = im[q];
                re[r] = c * a0 + s * b1;  im[r] = c * b0 - s * a1;
                re[q] = c * a1 + s * b0;  im[q] = c * b1 - s * a0;
            }
        }
    };
    auto rz_reg = [&](int rm, float c, float s) {
        #pragma unroll
        for (int r = 0; r < 32; ++r) {
            float sg = (r & rm) ? s : -s;
            float nr = c * re[r] - sg * im[r];
            im[r]    = c * im[r] + sg * re[r];
            re[r]    = nr;
        }
    };

    // --- circuit ---
    ry_lane(8, qc[0], qs[0]);     // ry w0
    rx_lane(1, qc[1], qs[1]);     // rx w3
    cnot_ll(8, 4);                // cnot 0,1
    rz_reg(8, qc[2], qs[2]);      // rz w5
    ry_reg(2, qc[3], qs[3]);      // ry w7
    cnot_ll(2, 1);                // cnot 2,3
    rx_lane(4, qc[4], qs[4]);     // rx w1
    rz_reg(1, qc[5], qs[5]);      // rz w8
    {                              // cnot 4,5: ctrl r bit4, flip r bit3
        #pragma unroll
        for (int k = 16; k < 24; ++k) {
            float t;
            t = re[k]; re[k] = re[k+8]; re[k+8] = t;
            t = im[k]; im[k] = im[k+8]; im[k+8] = t;
        }
    }
    ry_lane(2, qc[6], qs[6]);     // ry w2
    rx_reg(4, qc[7], qs[7]);      // rx w6
    {                              // cnot 6,7: ctrl r bit2, flip r bit1
        #pragma unroll
        for (int b = 0; b < 32; b += 8) {
            float t;
            t = re[b+4]; re[b+4] = re[b+6]; re[b+6] = t;
            t = im[b+4]; im[b+4] = im[b+6]; im[b+6] = t;
            t = re[b+5]; re[b+5] = re[b+7]; re[b+7] = t;
            t = im[b+5]; im[b+5] = im[b+7]; im[b+7] = t;
        }
    }
    rz_reg(16, qc[8], qs[8]);     // rz w4
    ry_reg(1,  qc[9], qs[9]);     // ry w8
    {                              // cnot 8,0: ctrl r bit0, tgt lane mask 8
        #pragma unroll
        for (int r = 1; r < 32; r += 2) {
            re[r] = __shfl_xor(re[r], 8);
            im[r] = __shfl_xor(im[r], 8);
        }
    }
    rx_reg(8, qc[10], qs[10]);    // rx w5

    // --- expectations: signed Hadamard tree over reg bits ---
    float pb[32];
    #pragma unroll
    for (int r = 0; r < 32; ++r)
        pb[r] = re[r] * re[r] + im[r] * im[r];
    float a4, a5 = 0.0f, a6 = 0.0f, a7 = 0.0f, a8 = 0.0f;
    float t16[16];
    #pragma unroll
    for (int k = 0; k < 16; ++k) { t16[k] = pb[2*k] + pb[2*k+1]; a8 += pb[2*k] - pb[2*k+1]; }
    float t8[8];
    #pragma unroll
    for (int k = 0; k < 8; ++k)  { t8[k] = t16[2*k] + t16[2*k+1]; a7 += t16[2*k] - t16[2*k+1]; }
    float t4[4];
    #pragma unroll
    for (int k = 0; k < 4; ++k)  { t4[k] = t8[2*k] + t8[2*k+1]; a6 += t8[2*k] - t8[2*k+1]; }
    float t2[2];
    #pragma unroll
    for (int k = 0; k < 2; ++k)  { t2[k] = t4[2*k] + t4[2*k+1]; a5 += t4[2*k] - t4[2*k+1]; }
    float ptot = t2[0] + t2[1];
    a4 = t2[0] - t2[1];

    float acc[9];
    acc[0] = (l4 & 8) ? -ptot : ptot;
    acc[1] = (l4 & 4) ? -ptot : ptot;
    acc[2] = (l4 & 2) ? -ptot : ptot;
    acc[3] = (l4 & 1) ? -ptot : ptot;
    acc[4] = a4; acc[5] = a5; acc[6] = a6; acc[7] = a7; acc[8] = a8;
    #pragma unroll
    for (int m = 1; m < 16; m <<= 1) {
        #pragma unroll
        for (int w = 0; w < 9; ++w)
            acc[w] += __shfl_xor(acc[w], m);
    }
    if (l4 == 0) {
        #pragma unroll
        for (int w = 0; w < 9; ++w)
            feats[patch * 9 + w] = acc[w];
    }
}

// One wave per image: 2 dot products of length 1521 + bias + log_softmax.
__global__ __launch_bounds__(256) void head_kernel(const float* __restrict__ feats,
                                                   const float* __restrict__ W,
                                                   const float* __restrict__ bias,
                                                   float* __restrict__ out) {
    const int wave = (blockIdx.x * blockDim.x + threadIdx.x) >> 6;
    const int lane = threadIdx.x & 63;
    if (wave >= 1024) return;
    const float* f = feats + wave * FEAT;
    float s0 = 0.0f, s1 = 0.0f;
    for (int j = lane; j < FEAT; j += 64) {
        float v = f[j];
        s0 += v * W[j];
        s1 += v * W[FEAT + j];
    }
    #pragma unroll
    for (int m = 1; m < 64; m <<= 1) {
        s0 += __shfl_xor(s0, m);
        s1 += __shfl_xor(s1, m);
    }
    if (lane == 0) {
        float l0 = s0 + bias[0];
        float l1 = s1 + bias[1];
        float mx  = fmaxf(l0, l1);
        float lse = mx + logf(expf(l0 - mx) + expf(l1 - mx));
        out[wave * 2 + 0] = l0 - lse;
        out[wave * 2 + 1] = l1 - lse;
    }
}

extern "C" void kernel_launch(void* const* d_in, const int* in_sizes, int n_in,
                              void* d_out, int out_size, void* d_ws, size_t ws_size,
                              hipStream_t stream) {
    const float* x  = (const float*)d_in[0];   // (1024,1,28,28)
    const float* qp = (const float*)d_in[1];   // (11,)
    const float* W  = (const float*)d_in[2];   // (2,1521)
    const float* b  = (const float*)d_in[3];   // (2,)
    float* out   = (float*)d_out;              // (1024,2) f32
    float* feats = (float*)d_ws;               // 1024*1521 f32 = 6.23 MB

    // M_TOTAL/4 waves, 4 waves per block
    quanv_kernel<<<M_TOTAL / 16, 256, 0, stream>>>(x, qp, feats);
    head_kernel<<<1024 / 4, 256, 0, stream>>>(feats, W, b, out);
}

// Round 3
// 135.476 us; speedup vs baseline: 2.3683x; 1.4223x over previous
//
#include <hip/hip_runtime.h>
#include <math.h>

// Problem constants
#define IMG 28
#define NPP 169            // 13*13 patches per image
#define M_TOTAL (1024*NPP) // 173056 patches
#define FEAT 1521          // 169*9

__device__ __forceinline__ float rfl(float v) {
    return __int_as_float(__builtin_amdgcn_readfirstlane(__float_as_int(v)));
}

// Lane-xor via DPP (VALU pipe, not DS pipe).
//   xor1: quad_perm [1,0,3,2]  -> ctrl 0xB1
//   xor2: quad_perm [2,3,0,1]  -> ctrl 0x4E
//   xor8: row_ror:8 (within 16-lane row, (i+8)&15 == i^8) -> ctrl 0x128
template<int CTRL>
__device__ __forceinline__ float dppf(float v) {
    return __int_as_float(__builtin_amdgcn_update_dpp(
        0, __float_as_int(v), CTRL, 0xF, 0xF, true));
}

// 4 patches per wave; 16 lanes per patch; 32 complex amplitudes per lane.
// Basis index d: wire w bit is bit (8-w) of d.
// Lane-bit mapping (chosen so the only non-DPP mask, xor-4, carries one gate):
//   w0 -> lane bit3 (mask 8, DPP ror8)
//   w1 -> lane bit1 (mask 2, DPP quad)
//   w2 -> lane bit2 (mask 4, ds_swizzle)   [only gate: ry w2]
//   w3 -> lane bit0 (mask 1, DPP quad)
//   w4..w8 -> register bits 4..0 (rm = 16,8,4,2,1)
__global__ __launch_bounds__(256) void quanv_kernel(const float* __restrict__ x,
                                                    const float* __restrict__ qp,
                                                    float* __restrict__ feats) {
    const int wid  = (blockIdx.x * blockDim.x + threadIdx.x) >> 6;
    const int lane = threadIdx.x & 63;
    const int sub  = lane >> 4;     // patch-in-wave
    const int l4   = lane & 15;     // lane-in-patch
    const int patch = wid * 4 + sub;
    const int img = patch / NPP;
    const int rem = patch - img * NPP;
    const int pr  = rem / 13;
    const int pc  = rem - pr * 13;
    const float* base = x + img * (IMG*IMG) + (pr * 2) * IMG + pc * 2;

    // --- per-patch data-encoding trig (wire w = a*3 + c) ---
    float cw[9], sw[9];
    #pragma unroll
    for (int a = 0; a < 3; ++a)
        #pragma unroll
        for (int c = 0; c < 3; ++c) {
            float h = 0.5f * base[a * IMG + c];
            cw[a*3+c] = __cosf(h);
            sw[a*3+c] = __sinf(h);
        }

    // --- parameter trig, wave-uniform -> SGPRs ---
    float qc[11], qs[11];
    #pragma unroll
    for (int p = 0; p < 11; ++p) {
        float h = 0.5f * qp[p];
        qc[p] = rfl(__cosf(h));
        qs[p] = rfl(__sinf(h));
    }

    // lane-bit tests per wire
    const bool b0 = (l4 & 8) != 0;   // w0
    const bool b1 = (l4 & 2) != 0;   // w1
    const bool b2 = (l4 & 4) != 0;   // w2
    const bool b3 = (l4 & 1) != 0;   // w3

    // --- initial product state ---
    float L = 1.0f;
    L *= b0 ? sw[0] : cw[0];
    L *= b1 ? sw[1] : cw[1];
    L *= b2 ? sw[2] : cw[2];
    L *= b3 ? sw[3] : cw[3];
    float Lf[4];
    Lf[0] = L * (cw[4]*cw[5]); Lf[1] = L * (cw[4]*sw[5]);
    Lf[2] = L * (sw[4]*cw[5]); Lf[3] = L * (sw[4]*sw[5]);
    float f678[8];
    #pragma unroll
    for (int i = 0; i < 8; ++i)
        f678[i] = ((i&4)?sw[6]:cw[6]) * ((i&2)?sw[7]:cw[7]) * ((i&1)?sw[8]:cw[8]);
    float re[32], im[32];
    #pragma unroll
    for (int r = 0; r < 32; ++r) {
        re[r] = Lf[r >> 3] * f678[r & 7];
        im[r] = 0.0f;
    }

    // lane-shuffle functors
    auto shx1 = [](float v) { return dppf<0xB1>(v); };
    auto shx2 = [](float v) { return dppf<0x4E>(v); };
    auto shx8 = [](float v) { return dppf<0x128>(v); };
    auto shx4 = [](float v) { return __shfl_xor(v, 4); };

    // --- gate helpers ---
    auto ry_lane = [&](auto&& sh, bool bit, float c, float s) {
        float sg = bit ? s : -s;
        #pragma unroll
        for (int r = 0; r < 32; ++r) {
            float pre = sh(re[r]);
            float pim = sh(im[r]);
            re[r] = c * re[r] + sg * pre;
            im[r] = c * im[r] + sg * pim;
        }
    };
    auto rx_lane = [&](auto&& sh, float c, float s) {
        #pragma unroll
        for (int r = 0; r < 32; ++r) {
            float pre = sh(re[r]);
            float pim = sh(im[r]);
            re[r] = c * re[r] + s * pim;
            im[r] = c * im[r] - s * pre;
        }
    };
    auto cnot_ll = [&](auto&& sh, bool ctrl) {
        #pragma unroll
        for (int r = 0; r < 32; ++r) {
            float pre = sh(re[r]);
            float pim = sh(im[r]);
            re[r] = ctrl ? pre : re[r];
            im[r] = ctrl ? pim : im[r];
        }
    };
    auto ry_reg = [&](int rm, float c, float s) {
        #pragma unroll
        for (int r = 0; r < 32; ++r) {
            if (!(r & rm)) {
                int q = r | rm;
                float a0 = re[r], a1 = re[q], g0 = im[r], g1 = im[q];
                re[r] = c * a0 - s * a1;  re[q] = s * a0 + c * a1;
                im[r] = c * g0 - s * g1;  im[q] = s * g0 + c * g1;
            }
        }
    };
    auto rx_reg = [&](int rm, float c, float s) {
        #pragma unroll
        for (int r = 0; r < 32; ++r) {
            if (!(r & rm)) {
                int q = r | rm;
                float a0 = re[r], a1 = re[q], g0 = im[r], g1 = im[q];
                re[r] = c * a0 + s * g1;  im[r] = c * g0 - s * a1;
                re[q] = c * a1 + s * g0;  im[q] = c * g1 - s * a0;
            }
        }
    };
    auto rz_reg = [&](int rm, float c, float s) {
        #pragma unroll
        for (int r = 0; r < 32; ++r) {
            float sg = (r & rm) ? s : -s;
            float nr = c * re[r] - sg * im[r];
            im[r]    = c * im[r] + sg * re[r];
            re[r]    = nr;
        }
    };

    // --- circuit ---
    ry_lane(shx8, b0, qc[0], qs[0]);   // ry w0
    rx_lane(shx1, qc[1], qs[1]);       // rx w3
    cnot_ll(shx2, b0);                 // cnot 0,1 (ctrl w0, tgt w1)
    rz_reg(8, qc[2], qs[2]);           // rz w5
    ry_reg(2, qc[3], qs[3]);           // ry w7
    cnot_ll(shx1, b2);                 // cnot 2,3 (ctrl w2, tgt w3)
    rx_lane(shx2, qc[4], qs[4]);       // rx w1
    rz_reg(1, qc[5], qs[5]);           // rz w8
    {                                   // cnot 4,5: ctrl reg bit4, flip reg bit3
        #pragma unroll
        for (int k = 16; k < 24; ++k) {
            float t;
            t = re[k]; re[k] = re[k+8]; re[k+8] = t;
            t = im[k]; im[k] = im[k+8]; im[k+8] = t;
        }
    }
    ry_lane(shx4, b2, qc[6], qs[6]);   // ry w2 (the one ds_swizzle gate)
    rx_reg(4, qc[7], qs[7]);           // rx w6
    {                                   // cnot 6,7: ctrl reg bit2, flip reg bit1
        #pragma unroll
        for (int b = 0; b < 32; b += 8) {
            float t;
            t = re[b+4]; re[b+4] = re[b+6]; re[b+6] = t;
            t = im[b+4]; im[b+4] = im[b+6]; im[b+6] = t;
            t = re[b+5]; re[b+5] = re[b+7]; re[b+7] = t;
            t = im[b+5]; im[b+5] = im[b+7]; im[b+7] = t;
        }
    }
    rz_reg(16, qc[8], qs[8]);          // rz w4
    ry_reg(1,  qc[9], qs[9]);          // ry w8
    {                                   // cnot 8,0: ctrl reg bit0, tgt w0 (lane mask 8)
        #pragma unroll
        for (int r = 1; r < 32; r += 2) {
            re[r] = shx8(re[r]);
            im[r] = shx8(im[r]);
        }
    }
    rx_reg(8, qc[10], qs[10]);         // rx w5

    // --- expectations: signed Hadamard tree over reg bits ---
    float pb[32];
    #pragma unroll
    for (int r = 0; r < 32; ++r)
        pb[r] = re[r] * re[r] + im[r] * im[r];
    float a4, a5 = 0.0f, a6 = 0.0f, a7 = 0.0f, a8 = 0.0f;
    float t16[16];
    #pragma unroll
    for (int k = 0; k < 16; ++k) { t16[k] = pb[2*k] + pb[2*k+1]; a8 += pb[2*k] - pb[2*k+1]; }
    float t8[8];
    #pragma unroll
    for (int k = 0; k < 8; ++k)  { t8[k] = t16[2*k] + t16[2*k+1]; a7 += t16[2*k] - t16[2*k+1]; }
    float t4[4];
    #pragma unroll
    for (int k = 0; k < 4; ++k)  { t4[k] = t8[2*k] + t8[2*k+1]; a6 += t8[2*k] - t8[2*k+1]; }
    float t2[2];
    #pragma unroll
    for (int k = 0; k < 2; ++k)  { t2[k] = t4[2*k] + t4[2*k+1]; a5 += t4[2*k] - t4[2*k+1]; }
    float ptot = t2[0] + t2[1];
    a4 = t2[0] - t2[1];

    float acc[9];
    acc[0] = b0 ? -ptot : ptot;
    acc[1] = b1 ? -ptot : ptot;
    acc[2] = b2 ? -ptot : ptot;
    acc[3] = b3 ? -ptot : ptot;
    acc[4] = a4; acc[5] = a5; acc[6] = a6; acc[7] = a7; acc[8] = a8;

    // 16-lane butterfly: DPP for 1,2,8; ds_swizzle for 4
    #pragma unroll
    for (int w = 0; w < 9; ++w) acc[w] += shx1(acc[w]);
    #pragma unroll
    for (int w = 0; w < 9; ++w) acc[w] += shx2(acc[w]);
    #pragma unroll
    for (int w = 0; w < 9; ++w) acc[w] += shx4(acc[w]);
    #pragma unroll
    for (int w = 0; w < 9; ++w) acc[w] += shx8(acc[w]);

    if (l4 == 0) {
        #pragma unroll
        for (int w = 0; w < 9; ++w)
            feats[patch * 9 + w] = acc[w];
    }
}

// One wave per image: 2 dot products of length 1521 + bias + log_softmax.
__global__ __launch_bounds__(256) void head_kernel(const float* __restrict__ feats,
                                                   const float* __restrict__ W,
                                                   const float* __restrict__ bias,
                                                   float* __restrict__ out) {
    const int wave = (blockIdx.x * blockDim.x + threadIdx.x) >> 6;
    const int lane = threadIdx.x & 63;
    if (wave >= 1024) return;
    const float* f = feats + wave * FEAT;
    float s0 = 0.0f, s1 = 0.0f;
    for (int j = lane; j < FEAT; j += 64) {
        float v = f[j];
        s0 += v * W[j];
        s1 += v * W[FEAT + j];
    }
    #pragma unroll
    for (int m = 1; m < 64; m <<= 1) {
        s0 += __shfl_xor(s0, m);
        s1 += __shfl_xor(s1, m);
    }
    if (lane == 0) {
        float l0 = s0 + bias[0];
        float l1 = s1 + bias[1];
        float mx  = fmaxf(l0, l1);
        float lse = mx + logf(expf(l0 - mx) + expf(l1 - mx));
        out[wave * 2 + 0] = l0 - lse;
        out[wave * 2 + 1] = l1 - lse;
    }
}

extern "C" void kernel_launch(void* const* d_in, const int* in_sizes, int n_in,
                              void* d_out, int out_size, void* d_ws, size_t ws_size,
                              hipStream_t stream) {
    const float* x  = (const float*)d_in[0];   // (1024,1,28,28)
    const float* qp = (const float*)d_in[1];   // (11,)
    const float* W  = (const float*)d_in[2];   // (2,1521)
    const float* b  = (const float*)d_in[3];   // (2,)
    float* out   = (float*)d_out;              // (1024,2) f32
    float* feats = (float*)d_ws;               // 1024*1521 f32 = 6.23 MB

    quanv_kernel<<<M_TOTAL / 16, 256, 0, stream>>>(x, qp, feats);
    head_kernel<<<1024 / 4, 256, 0, stream>>>(feats, W, b, out);
}

// Round 4
// 9.332 us; speedup vs baseline: 34.3810x; 14.5170x over previous
//
#include <hip/hip_runtime.h>
#include <math.h>

// Closed-form collapse of the quanv circuit:
//  - all pre-entanglement rotations folded into the per-wire product state
//  - rx w1 / ry w2 / rx w5 commuted to the end -> Heisenberg corrections
//  - 5 CNOTs (Clifford) pull each Z_w back to a Pauli string
//  - Pauli-string expectation on a product state factorizes per wire
// Per patch (C_w = cos(pixel_w), S_w = sin(pixel_w); cq/sq = cos/sin of full
// q_params angles):
//   z0 = C0 cq0 - S0 sq0
//   z8 = cq9 C8 - cq5 sq9 S8
//   z6 = cq7 C6
//   E0 = z0 z8
//   E1 = cq4 z0 C1
//   E2 = cq6 C2 - sq6 S2 S3
//   E3 = cq1 C2 C3
//   E4 = C4
//   E5 = C4 (cq10 C5 + sq10 sq2 S5)
//   E6 = z6
//   E7 = z6 (cq3 C7 - sq3 S7)
//   E8 = z8

#define IMG 28
#define NPIX (IMG*IMG)
#define NPP 169            // 13*13 patches per image
#define FEAT 1521          // 169*9

__global__ __launch_bounds__(256) void fused_kernel(
    const float* __restrict__ x, const float* __restrict__ qp,
    const float* __restrict__ W, const float* __restrict__ bias,
    float* __restrict__ out)
{
    __shared__ float csA[NPIX], snA[NPIX];
    __shared__ float Wl[2 * FEAT];
    __shared__ float red0[4], red1[4];

    const int img = blockIdx.x;
    const int tid = threadIdx.x;

    // full-angle parameter trig (wave-uniform, cheap)
    float cq[11], sq[11];
    #pragma unroll
    for (int p = 0; p < 11; ++p)
        __sincosf(qp[p], &sq[p], &cq[p]);

    // stage W coalesced into LDS (12 KB, reused by whole block)
    for (int i = tid; i < 2 * FEAT; i += 256)
        Wl[i] = W[i];

    // per-pixel full-angle trig
    const float* xi = x + img * NPIX;
    for (int i = tid; i < NPIX; i += 256) {
        float s, c;
        __sincosf(xi[i], &s, &c);
        csA[i] = c;
        snA[i] = s;
    }
    __syncthreads();

    float s0 = 0.0f, s1 = 0.0f;
    if (tid < NPP) {
        const int pr = tid / 13;
        const int pc = tid - pr * 13;
        const int base = (pr * 2) * IMG + pc * 2;

        float C[9], S[9];
        #pragma unroll
        for (int a = 0; a < 3; ++a)
            #pragma unroll
            for (int c = 0; c < 3; ++c) {
                int ix = base + a * IMG + c;
                C[a*3+c] = csA[ix];
                S[a*3+c] = snA[ix];
            }

        const float z0 = C[0]*cq[0] - S[0]*sq[0];
        const float z8 = cq[9]*C[8] - cq[5]*sq[9]*S[8];
        const float z6 = cq[7]*C[6];

        float E[9];
        E[0] = z0 * z8;
        E[1] = cq[4] * z0 * C[1];
        E[2] = cq[6]*C[2] - sq[6]*S[2]*S[3];
        E[3] = cq[1]*C[2]*C[3];
        E[4] = C[4];
        E[5] = C[4]*(cq[10]*C[5] + sq[10]*sq[2]*S[5]);
        E[6] = z6;
        E[7] = z6*(cq[3]*C[7] - sq[3]*S[7]);
        E[8] = z8;

        const float* W0 = Wl + tid * 9;
        const float* W1 = Wl + FEAT + tid * 9;
        #pragma unroll
        for (int w = 0; w < 9; ++w) {
            s0 += E[w] * W0[w];
            s1 += E[w] * W1[w];
        }
    }

    // block reduction: wave butterfly then cross-wave via LDS
    #pragma unroll
    for (int m = 1; m < 64; m <<= 1) {
        s0 += __shfl_xor(s0, m);
        s1 += __shfl_xor(s1, m);
    }
    const int wv = tid >> 6;
    if ((tid & 63) == 0) { red0[wv] = s0; red1[wv] = s1; }
    __syncthreads();
    if (tid == 0) {
        float l0 = red0[0] + red0[1] + red0[2] + red0[3] + bias[0];
        float l1 = red1[0] + red1[1] + red1[2] + red1[3] + bias[1];
        float mx  = fmaxf(l0, l1);
        float lse = mx + __logf(__expf(l0 - mx) + __expf(l1 - mx));
        out[img * 2 + 0] = l0 - lse;
        out[img * 2 + 1] = l1 - lse;
    }
}

extern "C" void kernel_launch(void* const* d_in, const int* in_sizes, int n_in,
                              void* d_out, int out_size, void* d_ws, size_t ws_size,
                              hipStream_t stream) {
    const float* x  = (const float*)d_in[0];   // (1024,1,28,28)
    const float* qp = (const float*)d_in[1];   // (11,)
    const float* W  = (const float*)d_in[2];   // (2,1521)
    const float* b  = (const float*)d_in[3];   // (2,)
    float* out = (float*)d_out;                // (1024,2) f32

    fused_kernel<<<1024, 256, 0, stream>>>(x, qp, W, b, out);
}